// Round 7
// baseline (175.275 us; speedup 1.0000x reference)
//
#include <hip/hip_runtime.h>
#include <hip/hip_bf16.h>

// Problem: b=8, n=25, t=64, C=512, PC=128, heads=8, d=16
// Inputs fp32 (bf16-exact values), output fp32; harness threshold ~9.75e-2.
#define BUF   1638400ull      // 12800*128 elements
#define QSC   0.36067376f     // 0.25 * log2(e): folded into Q; exp -> exp2

typedef __attribute__((ext_vector_type(4)))  float    f4;
typedef __attribute__((ext_vector_type(16))) float    f16v;
typedef __attribute__((ext_vector_type(8)))  short    s8v;
typedef __attribute__((ext_vector_type(4)))  unsigned u4v;

#if __has_builtin(__builtin_amdgcn_exp2f)
#define EXP2(x) __builtin_amdgcn_exp2f(x)
#else
#define EXP2(x) exp2f(x)
#endif
#if __has_builtin(__builtin_amdgcn_rcpf)
#define RCP(x) __builtin_amdgcn_rcpf(x)
#else
#define RCP(x) (1.0f/(x))
#endif

__device__ __forceinline__ short f2bf(float f) {
    __hip_bfloat16 h = __float2bfloat16(f);
    short s; __builtin_memcpy(&s, &h, 2); return s;
}
__device__ __forceinline__ unsigned pack2(float a, float b) {
    return (unsigned)(unsigned short)f2bf(a) | ((unsigned)(unsigned short)f2bf(b) << 16);
}
__device__ __forceinline__ float bf2f(short s) {
    return __uint_as_float((unsigned)(unsigned short)s << 16);
}
__device__ __forceinline__ unsigned tpack(float hi, float lo) { // trunc pair
    return __builtin_amdgcn_perm(__float_as_uint(hi), __float_as_uint(lo), 0x07060302u);
}
__device__ __forceinline__ f16v zf16() {
    f16v z;
#pragma unroll
    for (int i = 0; i < 16; i++) z[i] = 0.f;
    return z;
}

// ---------------------------------------------------------------------------
// Kernel 0: prep — 6 weight mats -> bf16 B-frag order + ones buffer.
// ---------------------------------------------------------------------------
__global__ __launch_bounds__(256) void prep(
    const float* __restrict__ wq0, const float* __restrict__ wq1,
    const float* __restrict__ wq2,
    const float* __restrict__ wp0, const float* __restrict__ wp1,
    const float* __restrict__ wp2,
    short* __restrict__ wsw, short* __restrict__ onesb)
{
    const int blk = blockIdx.x, tid = threadIdx.x;
    if (blk < 96) {
        const int idx0 = blk * 2048 + tid * 8;
        const float* W; int Ncols, loc = idx0;
        if      (idx0 < 49152)  { W = wq0; Ncols = 384; }
        else if (idx0 < 98304)  { W = wq1; Ncols = 384; loc -= 49152; }
        else if (idx0 < 147456) { W = wq2; Ncols = 384; loc -= 98304; }
        else if (idx0 < 163840) { W = wp0; Ncols = 128; loc -= 147456; }
        else if (idx0 < 180224) { W = wp1; Ncols = 128; loc -= 163840; }
        else                    { W = wp2; Ncols = 128; loc -= 180224; }
        const int lane = (loc >> 3) & 63, ks = (loc >> 9) & 3, nt = loc >> 11;
        const int col = nt * 16 + (lane & 15);
        const int k0  = ks * 32 + 8 * (lane >> 4);
        s8v o;
#pragma unroll
        for (int j = 0; j < 8; j++) o[j] = f2bf(W[(k0 + j) * Ncols + col]);
        *(s8v*)(wsw + idx0) = o;
    } else {
        s8v o;
#pragma unroll
        for (int j = 0; j < 8; j++) o[j] = (short)0x3F80;   // bf16 1.0
        *(s8v*)(onesb + tid * 8) = o;
    }
}

// ---------------------------------------------------------------------------
// Kernel 1: fused QKV for all branches -> bf16, V transposed per branch.
// Round-7: 1-deep software pipeline of weight frags + bias across nti
// (hides ~200cy L2 latency per iteration behind MFMA/store of previous).
// ---------------------------------------------------------------------------
__global__ __launch_bounds__(256) void qkv_all(
    const float* __restrict__ x, const short* __restrict__ wsw,
    const float* __restrict__ bq0, const float* __restrict__ bq1,
    const float* __restrict__ bq2,
    short* __restrict__ q0, short* __restrict__ k0, short* __restrict__ vt0,
    short* __restrict__ q1, short* __restrict__ k1, short* __restrict__ vt1,
    short* __restrict__ q2, short* __restrict__ k2, short* __restrict__ vt2)
{
    const int br = blockIdx.x / 800, tile = blockIdx.x % 800;
    const int tok0 = tile * 16;
    const int wave = threadIdx.x >> 6, lane = threadIdx.x & 63;
    const int c = lane & 15, gq = lane >> 4;
    const int off = 384 - 128 * br;
    const short* wswb = wsw + br * 49152;
    const float* bias = (br == 0) ? bq0 : (br == 1) ? bq1 : bq2;

    const float* xrow = x + (size_t)(tok0 + c) * 512 + off + 8 * gq;
    s8v af[4];
#pragma unroll
    for (int ks = 0; ks < 4; ks++) {
        float4 a = *(const float4*)(xrow + ks * 32);
        float4 b = *(const float4*)(xrow + ks * 32 + 4);
        u4v t;
        t[0] = tpack(a.y, a.x); t[1] = tpack(a.w, a.z);
        t[2] = tpack(b.y, b.x); t[3] = tpack(b.w, b.z);
        af[ks] = __builtin_bit_cast(s8v, t);
    }

    const int batch0 = tok0 >> 6;
    const int b_  = tok0 / 1600;
    const int rm0 = tok0 - b_ * 1600;
    const int seq1 = rm0 >> 6;

    // weight-frag pipeline: frag(nt,ks) at bpw + (nt*4+ks)*512
    const short* bpw = wswb + (size_t)lane * 8;
    const int nt0 = wave * 6;
    s8v bf0 = *(const s8v*)(bpw + (nt0 * 4 + 0) * 512);
    s8v bf1 = *(const s8v*)(bpw + (nt0 * 4 + 1) * 512);
    s8v bf2 = *(const s8v*)(bpw + (nt0 * 4 + 2) * 512);
    s8v bf3 = *(const s8v*)(bpw + (nt0 * 4 + 3) * 512);
    float bv = bias[nt0 * 16 + c];

    for (int nti = 0; nti < 6; nti++) {
        const int nt = nt0 + nti;
        s8v nf0, nf1, nf2, nf3; float bvn;
        if (nti < 5) {                       // prefetch nti+1 (uniform branch)
            nf0 = *(const s8v*)(bpw + ((nt + 1) * 4 + 0) * 512);
            nf1 = *(const s8v*)(bpw + ((nt + 1) * 4 + 1) * 512);
            nf2 = *(const s8v*)(bpw + ((nt + 1) * 4 + 2) * 512);
            nf3 = *(const s8v*)(bpw + ((nt + 1) * 4 + 3) * 512);
            bvn = bias[(nt + 1) * 16 + c];
        }
        f4 acc = {0.f, 0.f, 0.f, 0.f};
        acc = __builtin_amdgcn_mfma_f32_16x16x32_bf16(af[0], bf0, acc, 0, 0, 0);
        acc = __builtin_amdgcn_mfma_f32_16x16x32_bf16(af[1], bf1, acc, 0, 0, 0);
        acc = __builtin_amdgcn_mfma_f32_16x16x32_bf16(af[2], bf2, acc, 0, 0, 0);
        acc = __builtin_amdgcn_mfma_f32_16x16x32_bf16(af[3], bf3, acc, 0, 0, 0);

        const float v0 = acc[0]+bv, v1 = acc[1]+bv, v2 = acc[2]+bv, v3 = acc[3]+bv;
        const int which = nt >> 3, h = nt & 7;

        if (br == 0) {
            const int seq0 = (tok0 & 63) + 4 * gq;
            if (which == 2) {
                unsigned* p = (unsigned*)(vt0 + ((size_t)(batch0*8+h)*16 + c)*64 + seq0);
                p[0] = pack2(v0, v1); p[1] = pack2(v2, v3);
            } else {
                short* p = (which ? k0 : q0) + (((size_t)(batch0*8+h)*64 + seq0)*16 + c);
                p[0]=f2bf(v0); p[16]=f2bf(v1); p[32]=f2bf(v2); p[48]=f2bf(v3);
            }
        } else if (br == 1) {
            const int bt0 = b_ * 64 + (rm0 & 63) + 4 * gq;
            if (which == 2) {
                short* p = vt1 + ((size_t)(bt0*8+h)*16 + c)*32 + seq1;   // r stride 8*16*32
                p[0]=f2bf(v0); p[4096]=f2bf(v1); p[8192]=f2bf(v2); p[12288]=f2bf(v3);
            } else {
                short* p = (which ? k1 : q1) + (((size_t)bt0*8+h)*25 + seq1)*16 + c;
                p[0]=f2bf(v0); p[3200]=f2bf(v1); p[6400]=f2bf(v2); p[9600]=f2bf(v3);
            }
        } else {
            const int seq0 = rm0 + 4 * gq;
            if (which == 2) {
                unsigned* p = (unsigned*)(vt2 + ((size_t)b_*128 + h*16 + c)*1600 + seq0);
                p[0] = pack2(v0, v1); p[1] = pack2(v2, v3);
            } else {
                short* p = (which ? k2 : q2) + (((size_t)b_*8+h)*1600 + seq0)*16 + c;
                p[0]=f2bf(v0); p[16]=f2bf(v1); p[32]=f2bf(v2); p[48]=f2bf(v3);
            }
        }
        bf0 = nf0; bf1 = nf1; bf2 = nf2; bf3 = nf3; bv = bvn;
    }
}

// ---------------------------------------------------------------------------
// Barrier-free 32x32 attention pieces (round-8 proven math).
// QK: mfma_32x32x16 (K=d=16); K A-rows via sigma=(1 2)(5 6) block-of-4 perm
// so exp'd C regs 0-7 / 8-15 ARE the PV1/PV2 A-frags.
// PV: B cols 16-31 = ones -> softmax denominator computed for free.
// R6: 3-deep named register pipeline + XCD-affinity block remap.
// ---------------------------------------------------------------------------
__device__ __forceinline__ s8v load_qfrag(const short* __restrict__ qg,
                                          const int qt0, const int lane)
{
    const int n = lane & 31, g2 = lane >> 5;
    s8v qraw = *(const s8v*)(qg + (size_t)(qt0 + n) * 16 + 8 * g2);
    u4v qu;
#pragma unroll
    for (int jp = 0; jp < 4; jp++)
        qu[jp] = tpack(bf2f(qraw[2*jp+1]) * QSC, bf2f(qraw[2*jp]) * QSC);
    return __builtin_bit_cast(s8v, qu);
}

template<bool MASK>
__device__ __forceinline__ f16v attn_loop(
    const short* __restrict__ kg, const short* __restrict__ vtg, const int vstride,
    const short* __restrict__ onesb, const s8v qf, const int lane,
    const int s0, const int s1)
{
    const int n = lane & 31, g2 = lane >> 5;
    const int b4 = n >> 2;
    const int krow = ((b4 ^ (((b4 ^ (b4 >> 1)) & 1) * 3)) << 2) + (n & 3);
    const short* kp = kg + (size_t)(s0 * 32 + krow) * 16 + 8 * g2;   // +512/step
    const short* vp;
    int vinc;
    if (n < 16) { vp = vtg + (size_t)n * vstride + s0 * 32 + 8 * g2; vinc = 32; }
    else        { vp = onesb + 8 * g2; vinc = 0; }

    // prologue: load step s0
    s8v kf  = *(const s8v*)kp;  kp += 512;
    s8v vf1 = *(const s8v*)vp;
    s8v vf2 = *(const s8v*)(vp + 16); vp += vinc;

    f16v oacc = zf16();
    for (int s = s0; s < s1; s++) {
        // prefetch step s+1 (one-step overrun is inside workspace: safe)
        s8v kn  = *(const s8v*)kp;  kp += 512;
        s8v vn1 = *(const s8v*)vp;
        s8v vn2 = *(const s8v*)(vp + 16); vp += vinc;

        f16v sacc = __builtin_amdgcn_mfma_f32_32x32x16_bf16(kf, qf, zf16(), 0, 0, 0);

        float p[16];
#pragma unroll
        for (int r = 0; r < 16; r++) {
            p[r] = EXP2(sacc[r]);
            if (MASK && r >= 9) { if (g2) p[r] = 0.f; }   // keys 25..31 (s branch)
        }
        u4v u1, u2;
        u1[0]=tpack(p[1],p[0]);   u1[1]=tpack(p[3],p[2]);
        u1[2]=tpack(p[5],p[4]);   u1[3]=tpack(p[7],p[6]);
        u2[0]=tpack(p[9],p[8]);   u2[1]=tpack(p[11],p[10]);
        u2[2]=tpack(p[13],p[12]); u2[3]=tpack(p[15],p[14]);
        s8v pf1 = __builtin_bit_cast(s8v, u1);
        s8v pf2 = __builtin_bit_cast(s8v, u2);

        oacc = __builtin_amdgcn_mfma_f32_32x32x16_bf16(pf1, vf1, oacc, 0, 0, 0);
        oacc = __builtin_amdgcn_mfma_f32_32x32x16_bf16(pf2, vf2, oacc, 0, 0, 0);

        kf = kn; vf1 = vn1; vf2 = vn2;
    }
    return oacc;
}

// Dual-qtile variant with 3-deep load pipeline (named buffers, static rotation).
__device__ __forceinline__ void attn_loop2(
    const short* __restrict__ kg, const short* __restrict__ vtg, const int vstride,
    const short* __restrict__ onesb, const s8v qfA, const s8v qfB, const int lane,
    const int s0, const int s1, f16v& oA, f16v& oB)
{
    const int n = lane & 31, g2 = lane >> 5;
    const int b4 = n >> 2;
    const int krow = ((b4 ^ (((b4 ^ (b4 >> 1)) & 1) * 3)) << 2) + (n & 3);
    const short* kp = kg + (size_t)(s0 * 32 + krow) * 16 + 8 * g2;   // +512/step
    const short* vp;
    int vinc;
    if (n < 16) { vp = vtg + (size_t)n * vstride + s0 * 32 + 8 * g2; vinc = 32; }
    else        { vp = onesb + 8 * g2; vinc = 0; }

    // 3-deep prologue (up to 3-step pointer overrun stays inside workspace)
    s8v kf0 = *(const s8v*)kp; kp += 512;
    s8v va0 = *(const s8v*)vp; s8v vb0 = *(const s8v*)(vp + 16); vp += vinc;
    s8v kf1 = *(const s8v*)kp; kp += 512;
    s8v va1 = *(const s8v*)vp; s8v vb1 = *(const s8v*)(vp + 16); vp += vinc;
    s8v kf2 = *(const s8v*)kp; kp += 512;
    s8v va2 = *(const s8v*)vp; s8v vb2 = *(const s8v*)(vp + 16); vp += vinc;

    oA = zf16(); oB = zf16();
    for (int s = s0; s < s1; s++) {
        f16v sA = __builtin_amdgcn_mfma_f32_32x32x16_bf16(kf0, qfA, zf16(), 0, 0, 0);
        f16v sB = __builtin_amdgcn_mfma_f32_32x32x16_bf16(kf0, qfB, zf16(), 0, 0, 0);

        float pA[16], pB[16];
#pragma unroll
        for (int r = 0; r < 16; r++) { pA[r] = EXP2(sA[r]); pB[r] = EXP2(sB[r]); }
        u4v a1, a2, b1, b2;
        a1[0]=tpack(pA[1],pA[0]);   a1[1]=tpack(pA[3],pA[2]);
        a1[2]=tpack(pA[5],pA[4]);   a1[3]=tpack(pA[7],pA[6]);
        a2[0]=tpack(pA[9],pA[8]);   a2[1]=tpack(pA[11],pA[10]);
        a2[2]=tpack(pA[13],pA[12]); a2[3]=tpack(pA[15],pA[14]);
        b1[0]=tpack(pB[1],pB[0]);   b1[1]=tpack(pB[3],pB[2]);
        b1[2]=tpack(pB[5],pB[4]);   b1[3]=tpack(pB[7],pB[6]);
        b2[0]=tpack(pB[9],pB[8]);   b2[1]=tpack(pB[11],pB[10]);
        b2[2]=tpack(pB[13],pB[12]); b2[3]=tpack(pB[15],pB[14]);
        s8v pfA1 = __builtin_bit_cast(s8v, a1);
        s8v pfA2 = __builtin_bit_cast(s8v, a2);
        s8v pfB1 = __builtin_bit_cast(s8v, b1);
        s8v pfB2 = __builtin_bit_cast(s8v, b2);

        oA = __builtin_amdgcn_mfma_f32_32x32x16_bf16(pfA1, va0, oA, 0, 0, 0);
        oB = __builtin_amdgcn_mfma_f32_32x32x16_bf16(pfB1, va0, oB, 0, 0, 0);
        oA = __builtin_amdgcn_mfma_f32_32x32x16_bf16(pfA2, vb0, oA, 0, 0, 0);
        oB = __builtin_amdgcn_mfma_f32_32x32x16_bf16(pfB2, vb0, oB, 0, 0, 0);

        // rotate pipeline and issue step s+3
        kf0 = kf1; va0 = va1; vb0 = vb1;
        kf1 = kf2; va1 = va2; vb1 = vb2;
        kf2 = *(const s8v*)kp; kp += 512;
        va2 = *(const s8v*)vp; vb2 = *(const s8v*)(vp + 16); vp += vinc;
    }
}

__device__ __forceinline__ void attn_epilogue(
    const f16v oacc, short* __restrict__ obase, const int orowstride,
    const int qt0, const int nq, const int lane)
{
    const int n = lane & 31, g2 = lane >> 5;
#pragma unroll
    for (int r = 0; r < 16; r++) {
        float l = __shfl_xor(oacc[r], 16);
        float o = oacc[r] * RCP(l);
        const int q = qt0 + (r & 3) + 8 * (r >> 2) + 4 * g2;
        if (n < 16 && q < nq)
            obase[(size_t)q * orowstride + n] = f2bf(o);
    }
}

// ---------------------------------------------------------------------------
// Kernel 2: ALL attention. st: dual-qtile job per block, 4 waves split the
// 50 K-steps, TREE combine. XCD-affinity remap: the 25 qpair-blocks of one
// bh share blockIdx%8 -> same XCD -> K/V slice (100KB) resident in its L2.
// blocks [0,1600): st | [1600,2400): t | [2400,3424): s
// ---------------------------------------------------------------------------
__global__ __launch_bounds__(256) void attn_all(
    const short* __restrict__ q0, const short* __restrict__ k0, const short* __restrict__ vt0,
    const short* __restrict__ q1, const short* __restrict__ k1, const short* __restrict__ vt1,
    const short* __restrict__ q2, const short* __restrict__ k2, const short* __restrict__ vt2,
    const short* __restrict__ onesb,
    short* __restrict__ ob0, short* __restrict__ ob1, short* __restrict__ ob2)
{
    __shared__ float red[2][2][64][17];  // 17.4 KB (st only), conflict-free stride
    const int blk = blockIdx.x;
    const int wave = threadIdx.x >> 6, lane = threadIdx.x & 63;

    if (blk < 1600) {                    // ---- st: N=1600; 2 qtiles, 4-way K split
        const int xcd = blk & 7, slot = blk >> 3;       // XCD-affinity remap
        const int bh  = xcd * 8 + slot / 25;            // all 25 qpairs of bh on 1 XCD
        const int qt0 = (slot % 25) * 64;
        const int batch = bh >> 3, h = bh & 7;
        const short* qg = q2 + (size_t)bh * 25600;
        const s8v qfA = load_qfrag(qg, qt0, lane);
        const s8v qfB = load_qfrag(qg, qt0 + 32, lane);
        const int s0 = (50 * wave) >> 2, s1 = (50 * (wave + 1)) >> 2;  // 12-13 steps
        f16v oA, oB;
        attn_loop2(k2 + (size_t)bh * 25600,
                   vt2 + (size_t)batch * 204800 + (size_t)h * 25600, 1600,
                   onesb, qfA, qfB, lane, s0, s1, oA, oB);

        // round 1: waves 2,3 publish; waves 0,1 accumulate partner (wave+2)
        if (wave >= 2) {
#pragma unroll
            for (int j = 0; j < 16; j++) {
                red[wave - 2][0][lane][j] = oA[j];
                red[wave - 2][1][lane][j] = oB[j];
            }
        }
        __syncthreads();
        if (wave < 2) {
#pragma unroll
            for (int j = 0; j < 16; j++) {
                oA[j] += red[wave][0][lane][j];
                oB[j] += red[wave][1][lane][j];
            }
        }
        __syncthreads();
        // round 2: wave0 publishes its B half, wave1 its A half (slot 0 reuse)
        if (wave == 0) {
#pragma unroll
            for (int j = 0; j < 16; j++) red[0][0][lane][j] = oB[j];
        } else if (wave == 1) {
#pragma unroll
            for (int j = 0; j < 16; j++) red[0][1][lane][j] = oA[j];
        }
        __syncthreads();
        short* obase = ob2 + (size_t)batch * 204800 + h * 16;
        if (wave == 0) {
#pragma unroll
            for (int j = 0; j < 16; j++) oA[j] += red[0][1][lane][j];
            attn_epilogue(oA, obase, 128, qt0, 1600, lane);
        } else if (wave == 1) {
#pragma unroll
            for (int j = 0; j < 16; j++) oB[j] += red[0][0][lane][j];
            attn_epilogue(oB, obase, 128, qt0 + 32, 1600, lane);
        }
    } else if (blk < 2400) {             // ---- t: N=64, 2 steps, 1 wave/job
        const int wid = (blk - 1600) * 4 + wave;
        const int bh = wid >> 1, qt0 = (wid & 1) * 32;
        const int bn = bh >> 3, h = bh & 7;
        const s8v qf = load_qfrag(q0 + (size_t)bh * 1024, qt0, lane);
        f16v oacc = attn_loop<false>(k0 + (size_t)bh * 1024,
                                     vt0 + (size_t)bh * 1024, 64,
                                     onesb, qf, lane, 0, 2);
        attn_epilogue(oacc, ob0 + (size_t)bn * 8192 + h * 16, 128, qt0, 64, lane);
    } else {                             // ---- s: N=25, 1 step, masked
        const int bh = (blk - 2400) * 4 + wave;   // bt*8 + h, < 4096
        const int bt = bh >> 3, h = bh & 7;
        const int b_ = bt >> 6, t_ = bt & 63;
        const s8v qf = load_qfrag(q1 + (size_t)bh * 400, 0, lane);
        f16v oacc = attn_loop<true>(k1 + (size_t)bh * 400,
                                    vt1 + (size_t)bh * 512, 32,
                                    onesb, qf, lane, 0, 1);
        attn_epilogue(oacc, ob1 + (size_t)b_ * 204800 + t_ * 128 + h * 16,
                      8192, 0, 25, lane);
    }
}

// ---------------------------------------------------------------------------
// Kernel 3: output projection (bf16 ob in, MFMA, fused shuffle store) + id copy.
// Round-7: full unroll + hoisted weight/bias prefetch (8 frags + 2 biases
// in flight before first MFMA).
// blocks [0,2400): proj (br = blk/800) | [2400,2600): id group
// ---------------------------------------------------------------------------
__global__ __launch_bounds__(256) void projid(
    const short* __restrict__ ob0, const short* __restrict__ ob1,
    const short* __restrict__ ob2, const short* __restrict__ wsw,
    const float* __restrict__ bp0, const float* __restrict__ bp1,
    const float* __restrict__ bp2,
    const float* __restrict__ x, float* __restrict__ out)
{
    __shared__ unsigned short xl[64 * 130];
    const int blk = blockIdx.x, tid = threadIdx.x;

    if (blk < 2400) {
        const int br = blk / 800, t8 = blk % 800;
        const short* obb = (br == 0) ? ob0 : (br == 1) ? ob1 : ob2;
        const float* bp  = (br == 0) ? bp0 : (br == 1) ? bp1 : bp2;
        const short* wswb = wsw + 147456 + br * 16384;
        const int grp = br + 1;
        const int tok0 = t8 * 16;
        const int wave = tid >> 6, lane = tid & 63;
        const int c = lane & 15, gq = lane >> 4;

        // hoist ALL weight frags + biases (static indices)
        s8v wf[2][4];
        float bvv[2];
#pragma unroll
        for (int nti = 0; nti < 2; nti++) {
            const int nt = wave * 2 + nti;
            const short* bpw = wswb + ((size_t)(nt * 4) * 64 + lane) * 8;
#pragma unroll
            for (int ks = 0; ks < 4; ks++)
                wf[nti][ks] = *(const s8v*)(bpw + ks * 512);
            bvv[nti] = bp[nt * 16 + c];
        }

        s8v af[4];
#pragma unroll
        for (int ks = 0; ks < 4; ks++)
            af[ks] = *(const s8v*)(obb + (size_t)(tok0 + c) * 128 + ks * 32 + 8 * gq);

        const int bnn = t8 >> 2, b_ = bnn / 25, n_ = bnn % 25;
        const int t0 = (t8 & 3) * 16 + 4 * gq;

#pragma unroll
        for (int nti = 0; nti < 2; nti++) {
            const int nt = wave * 2 + nti;
            f4 acc = {0.f, 0.f, 0.f, 0.f};
#pragma unroll
            for (int ks = 0; ks < 4; ks++)
                acc = __builtin_amdgcn_mfma_f32_16x16x32_bf16(af[ks], wf[nti][ks], acc, 0, 0, 0);
            const int c2 = nt * 16 + c;
            const float bv = bvv[nti];
            float4 st = {acc[0]+bv, acc[1]+bv, acc[2]+bv, acc[3]+bv};
            *(float4*)(out + (size_t)b_ * 819200 + (size_t)(c2 * 4 + grp) * 1600
                           + n_ * 64 + t0) = st;
        }
    } else {
        const int bn = blk - 2400;
        const int b_ = bn / 25, n_ = bn % 25;
        for (int idx = tid; idx < 8192; idx += 256) {
            int row = idx >> 7, c2 = idx & 127;
            xl[row * 130 + c2] =
                (unsigned short)(__float_as_uint(x[(size_t)(bn * 64 + row) * 512 + c2]) >> 16);
        }
        __syncthreads();
        const int t_ = tid & 63, cg = tid >> 6;
        const size_t base = (size_t)b_ * 819200 + (size_t)n_ * 64 + t_;
#pragma unroll
        for (int i = 0; i < 32; i++) {
            int c2 = cg + 4 * i;
            out[base + (size_t)(c2 * 4 + 0) * 1600] =
                __uint_as_float((unsigned)xl[t_ * 130 + c2] << 16);
        }
    }
}

// ---------------------------------------------------------------------------
extern "C" void kernel_launch(void* const* d_in, const int* in_sizes, int n_in,
                              void* d_out, int out_size, void* d_ws, size_t ws_size,
                              hipStream_t stream)
{
    const float* x        = (const float*)d_in[0];
    const float* t_wqkv   = (const float*)d_in[1];
    const float* t_bqkv   = (const float*)d_in[2];
    const float* t_wproj  = (const float*)d_in[3];
    const float* t_bproj  = (const float*)d_in[4];
    const float* s_wqkv   = (const float*)d_in[5];
    const float* s_bqkv   = (const float*)d_in[6];
    const float* s_wproj  = (const float*)d_in[7];
    const float* s_bproj  = (const float*)d_in[8];
    const float* st_wqkv  = (const float*)d_in[9];
    const float* st_bqkv  = (const float*)d_in[10];
    const float* st_wproj = (const float*)d_in[11];
    const float* st_bproj = (const float*)d_in[12];

    short* wsw   = (short*)d_ws;            // 196608
    short* onesb = wsw + 196608ull;         // 2048 of bf16 1.0
    short* q0  = onesb + 2048ull;
    short* k0  = q0 + BUF;
    short* vt0 = k0 + BUF;
    short* q1  = vt0 + BUF;
    short* k1  = q1 + BUF;
    short* vt1 = k1 + BUF;                  // padded: 4096*16*32 = 2097152
    short* q2  = vt1 + 2097152ull;
    short* k2  = q2 + BUF;
    short* vt2 = k2 + BUF;
    short* ob0 = vt2 + BUF;
    short* ob1 = ob0 + BUF;
    short* ob2 = ob1 + BUF;
    float* out = (float*)d_out;

    prep<<<97, 256, 0, stream>>>(t_wqkv, s_wqkv, st_wqkv,
                                 t_wproj, s_wproj, st_wproj, wsw, onesb);
    qkv_all<<<2400, 256, 0, stream>>>(x, wsw, t_bqkv, s_bqkv, st_bqkv,
                                      q0, k0, vt0, q1, k1, vt1, q2, k2, vt2);
    attn_all<<<3424, 256, 0, stream>>>(q0, k0, vt0, q1, k1, vt1, q2, k2, vt2,
                                       onesb, ob0, ob1, ob2);
    projid<<<2600, 256, 0, stream>>>(ob0, ob1, ob2, wsw,
                                     t_bproj, s_bproj, st_bproj, x, out);
}

// Round 8
// 163.023 us; speedup vs baseline: 1.0752x; 1.0752x over previous
//
#include <hip/hip_runtime.h>
#include <hip/hip_bf16.h>

// Problem: b=8, n=25, t=64, C=512, PC=128, heads=8, d=16
// Inputs fp32 (bf16-exact values), output fp32; harness threshold ~9.75e-2.
#define BUF   1638400ull      // 12800*128 elements
#define QSC   0.36067376f     // 0.25 * log2(e): folded into Q; exp -> exp2

typedef __attribute__((ext_vector_type(4)))  float    f4;
typedef __attribute__((ext_vector_type(16))) float    f16v;
typedef __attribute__((ext_vector_type(8)))  short    s8v;
typedef __attribute__((ext_vector_type(4)))  unsigned u4v;

#if __has_builtin(__builtin_amdgcn_exp2f)
#define EXP2(x) __builtin_amdgcn_exp2f(x)
#else
#define EXP2(x) exp2f(x)
#endif
#if __has_builtin(__builtin_amdgcn_rcpf)
#define RCP(x) __builtin_amdgcn_rcpf(x)
#else
#define RCP(x) (1.0f/(x))
#endif

__device__ __forceinline__ short f2bf(float f) {
    __hip_bfloat16 h = __float2bfloat16(f);
    short s; __builtin_memcpy(&s, &h, 2); return s;
}
__device__ __forceinline__ unsigned pack2(float a, float b) {
    return (unsigned)(unsigned short)f2bf(a) | ((unsigned)(unsigned short)f2bf(b) << 16);
}
__device__ __forceinline__ float bf2f(short s) {
    return __uint_as_float((unsigned)(unsigned short)s << 16);
}
__device__ __forceinline__ unsigned tpack(float hi, float lo) { // trunc pair
    return __builtin_amdgcn_perm(__float_as_uint(hi), __float_as_uint(lo), 0x07060302u);
}
__device__ __forceinline__ f16v zf16() {
    f16v z;
#pragma unroll
    for (int i = 0; i < 16; i++) z[i] = 0.f;
    return z;
}

// ---------------------------------------------------------------------------
// Kernel 0: prep — 6 weight mats -> bf16 B-frag order + ones buffer.
// ---------------------------------------------------------------------------
__global__ __launch_bounds__(256) void prep(
    const float* __restrict__ wq0, const float* __restrict__ wq1,
    const float* __restrict__ wq2,
    const float* __restrict__ wp0, const float* __restrict__ wp1,
    const float* __restrict__ wp2,
    short* __restrict__ wsw, short* __restrict__ onesb)
{
    const int blk = blockIdx.x, tid = threadIdx.x;
    if (blk < 96) {
        const int idx0 = blk * 2048 + tid * 8;
        const float* W; int Ncols, loc = idx0;
        if      (idx0 < 49152)  { W = wq0; Ncols = 384; }
        else if (idx0 < 98304)  { W = wq1; Ncols = 384; loc -= 49152; }
        else if (idx0 < 147456) { W = wq2; Ncols = 384; loc -= 98304; }
        else if (idx0 < 163840) { W = wp0; Ncols = 128; loc -= 147456; }
        else if (idx0 < 180224) { W = wp1; Ncols = 128; loc -= 163840; }
        else                    { W = wp2; Ncols = 128; loc -= 180224; }
        const int lane = (loc >> 3) & 63, ks = (loc >> 9) & 3, nt = loc >> 11;
        const int col = nt * 16 + (lane & 15);
        const int k0  = ks * 32 + 8 * (lane >> 4);
        s8v o;
#pragma unroll
        for (int j = 0; j < 8; j++) o[j] = f2bf(W[(k0 + j) * Ncols + col]);
        *(s8v*)(wsw + idx0) = o;
    } else {
        s8v o;
#pragma unroll
        for (int j = 0; j < 8; j++) o[j] = (short)0x3F80;   // bf16 1.0
        *(s8v*)(onesb + tid * 8) = o;
    }
}

// ---------------------------------------------------------------------------
// Kernel 1: fused QKV for all branches -> bf16, V transposed per branch.
// R7: 1-deep weight-frag pipeline. R8: __launch_bounds__(256,4) -> 128-VGPR
// budget so the allocator stops sinking the prefetch back to its use.
// ---------------------------------------------------------------------------
__global__ __launch_bounds__(256, 4) void qkv_all(
    const float* __restrict__ x, const short* __restrict__ wsw,
    const float* __restrict__ bq0, const float* __restrict__ bq1,
    const float* __restrict__ bq2,
    short* __restrict__ q0, short* __restrict__ k0, short* __restrict__ vt0,
    short* __restrict__ q1, short* __restrict__ k1, short* __restrict__ vt1,
    short* __restrict__ q2, short* __restrict__ k2, short* __restrict__ vt2)
{
    const int br = blockIdx.x / 800, tile = blockIdx.x % 800;
    const int tok0 = tile * 16;
    const int wave = threadIdx.x >> 6, lane = threadIdx.x & 63;
    const int c = lane & 15, gq = lane >> 4;
    const int off = 384 - 128 * br;
    const short* wswb = wsw + br * 49152;
    const float* bias = (br == 0) ? bq0 : (br == 1) ? bq1 : bq2;

    const float* xrow = x + (size_t)(tok0 + c) * 512 + off + 8 * gq;
    s8v af[4];
#pragma unroll
    for (int ks = 0; ks < 4; ks++) {
        float4 a = *(const float4*)(xrow + ks * 32);
        float4 b = *(const float4*)(xrow + ks * 32 + 4);
        u4v t;
        t[0] = tpack(a.y, a.x); t[1] = tpack(a.w, a.z);
        t[2] = tpack(b.y, b.x); t[3] = tpack(b.w, b.z);
        af[ks] = __builtin_bit_cast(s8v, t);
    }

    const int batch0 = tok0 >> 6;
    const int b_  = tok0 / 1600;
    const int rm0 = tok0 - b_ * 1600;
    const int seq1 = rm0 >> 6;

    // weight-frag pipeline: frag(nt,ks) at bpw + (nt*4+ks)*512
    const short* bpw = wswb + (size_t)lane * 8;
    const int nt0 = wave * 6;
    s8v bf0 = *(const s8v*)(bpw + (nt0 * 4 + 0) * 512);
    s8v bf1 = *(const s8v*)(bpw + (nt0 * 4 + 1) * 512);
    s8v bf2 = *(const s8v*)(bpw + (nt0 * 4 + 2) * 512);
    s8v bf3 = *(const s8v*)(bpw + (nt0 * 4 + 3) * 512);
    float bv = bias[nt0 * 16 + c];

    for (int nti = 0; nti < 6; nti++) {
        const int nt = nt0 + nti;
        s8v nf0, nf1, nf2, nf3; float bvn;
        if (nti < 5) {                       // prefetch nti+1 (uniform branch)
            nf0 = *(const s8v*)(bpw + ((nt + 1) * 4 + 0) * 512);
            nf1 = *(const s8v*)(bpw + ((nt + 1) * 4 + 1) * 512);
            nf2 = *(const s8v*)(bpw + ((nt + 1) * 4 + 2) * 512);
            nf3 = *(const s8v*)(bpw + ((nt + 1) * 4 + 3) * 512);
            bvn = bias[(nt + 1) * 16 + c];
        }
        f4 acc = {0.f, 0.f, 0.f, 0.f};
        acc = __builtin_amdgcn_mfma_f32_16x16x32_bf16(af[0], bf0, acc, 0, 0, 0);
        acc = __builtin_amdgcn_mfma_f32_16x16x32_bf16(af[1], bf1, acc, 0, 0, 0);
        acc = __builtin_amdgcn_mfma_f32_16x16x32_bf16(af[2], bf2, acc, 0, 0, 0);
        acc = __builtin_amdgcn_mfma_f32_16x16x32_bf16(af[3], bf3, acc, 0, 0, 0);

        const float v0 = acc[0]+bv, v1 = acc[1]+bv, v2 = acc[2]+bv, v3 = acc[3]+bv;
        const int which = nt >> 3, h = nt & 7;

        if (br == 0) {
            const int seq0 = (tok0 & 63) + 4 * gq;
            if (which == 2) {
                unsigned* p = (unsigned*)(vt0 + ((size_t)(batch0*8+h)*16 + c)*64 + seq0);
                p[0] = pack2(v0, v1); p[1] = pack2(v2, v3);
            } else {
                short* p = (which ? k0 : q0) + (((size_t)(batch0*8+h)*64 + seq0)*16 + c);
                p[0]=f2bf(v0); p[16]=f2bf(v1); p[32]=f2bf(v2); p[48]=f2bf(v3);
            }
        } else if (br == 1) {
            const int bt0 = b_ * 64 + (rm0 & 63) + 4 * gq;
            if (which == 2) {
                short* p = vt1 + ((size_t)(bt0*8+h)*16 + c)*32 + seq1;   // r stride 8*16*32
                p[0]=f2bf(v0); p[4096]=f2bf(v1); p[8192]=f2bf(v2); p[12288]=f2bf(v3);
            } else {
                short* p = (which ? k1 : q1) + (((size_t)bt0*8+h)*25 + seq1)*16 + c;
                p[0]=f2bf(v0); p[3200]=f2bf(v1); p[6400]=f2bf(v2); p[9600]=f2bf(v3);
            }
        } else {
            const int seq0 = rm0 + 4 * gq;
            if (which == 2) {
                unsigned* p = (unsigned*)(vt2 + ((size_t)b_*128 + h*16 + c)*1600 + seq0);
                p[0] = pack2(v0, v1); p[1] = pack2(v2, v3);
            } else {
                short* p = (which ? k2 : q2) + (((size_t)b_*8+h)*1600 + seq0)*16 + c;
                p[0]=f2bf(v0); p[16]=f2bf(v1); p[32]=f2bf(v2); p[48]=f2bf(v3);
            }
        }
        bf0 = nf0; bf1 = nf1; bf2 = nf2; bf3 = nf3; bv = bvn;
    }
}

// ---------------------------------------------------------------------------
// Barrier-free 32x32 attention pieces (round-8 proven math).
// QK: mfma_32x32x16 (K=d=16); K A-rows via sigma=(1 2)(5 6) block-of-4 perm
// so exp'd C regs 0-7 / 8-15 ARE the PV1/PV2 A-frags.
// PV: B cols 16-31 = ones -> softmax denominator computed for free.
// R6: 3-deep named register pipeline + XCD-affinity block remap.
// R8: launch_bounds(256,4): VGPR 72 was too small to HOLD the 3-deep
// pipeline — allocator sank the prefetches. 128-VGPR budget frees it.
// ---------------------------------------------------------------------------
__device__ __forceinline__ s8v load_qfrag(const short* __restrict__ qg,
                                          const int qt0, const int lane)
{
    const int n = lane & 31, g2 = lane >> 5;
    s8v qraw = *(const s8v*)(qg + (size_t)(qt0 + n) * 16 + 8 * g2);
    u4v qu;
#pragma unroll
    for (int jp = 0; jp < 4; jp++)
        qu[jp] = tpack(bf2f(qraw[2*jp+1]) * QSC, bf2f(qraw[2*jp]) * QSC);
    return __builtin_bit_cast(s8v, qu);
}

template<bool MASK>
__device__ __forceinline__ f16v attn_loop(
    const short* __restrict__ kg, const short* __restrict__ vtg, const int vstride,
    const short* __restrict__ onesb, const s8v qf, const int lane,
    const int s0, const int s1)
{
    const int n = lane & 31, g2 = lane >> 5;
    const int b4 = n >> 2;
    const int krow = ((b4 ^ (((b4 ^ (b4 >> 1)) & 1) * 3)) << 2) + (n & 3);
    const short* kp = kg + (size_t)(s0 * 32 + krow) * 16 + 8 * g2;   // +512/step
    const short* vp;
    int vinc;
    if (n < 16) { vp = vtg + (size_t)n * vstride + s0 * 32 + 8 * g2; vinc = 32; }
    else        { vp = onesb + 8 * g2; vinc = 0; }

    // prologue: load step s0
    s8v kf  = *(const s8v*)kp;  kp += 512;
    s8v vf1 = *(const s8v*)vp;
    s8v vf2 = *(const s8v*)(vp + 16); vp += vinc;

    f16v oacc = zf16();
    for (int s = s0; s < s1; s++) {
        // prefetch step s+1 (one-step overrun is inside workspace: safe)
        s8v kn  = *(const s8v*)kp;  kp += 512;
        s8v vn1 = *(const s8v*)vp;
        s8v vn2 = *(const s8v*)(vp + 16); vp += vinc;

        f16v sacc = __builtin_amdgcn_mfma_f32_32x32x16_bf16(kf, qf, zf16(), 0, 0, 0);

        float p[16];
#pragma unroll
        for (int r = 0; r < 16; r++) {
            p[r] = EXP2(sacc[r]);
            if (MASK && r >= 9) { if (g2) p[r] = 0.f; }   // keys 25..31 (s branch)
        }
        u4v u1, u2;
        u1[0]=tpack(p[1],p[0]);   u1[1]=tpack(p[3],p[2]);
        u1[2]=tpack(p[5],p[4]);   u1[3]=tpack(p[7],p[6]);
        u2[0]=tpack(p[9],p[8]);   u2[1]=tpack(p[11],p[10]);
        u2[2]=tpack(p[13],p[12]); u2[3]=tpack(p[15],p[14]);
        s8v pf1 = __builtin_bit_cast(s8v, u1);
        s8v pf2 = __builtin_bit_cast(s8v, u2);

        oacc = __builtin_amdgcn_mfma_f32_32x32x16_bf16(pf1, vf1, oacc, 0, 0, 0);
        oacc = __builtin_amdgcn_mfma_f32_32x32x16_bf16(pf2, vf2, oacc, 0, 0, 0);

        kf = kn; vf1 = vn1; vf2 = vn2;
    }
    return oacc;
}

// Dual-qtile variant with 3-deep load pipeline (named buffers, static rotation).
__device__ __forceinline__ void attn_loop2(
    const short* __restrict__ kg, const short* __restrict__ vtg, const int vstride,
    const short* __restrict__ onesb, const s8v qfA, const s8v qfB, const int lane,
    const int s0, const int s1, f16v& oA, f16v& oB)
{
    const int n = lane & 31, g2 = lane >> 5;
    const int b4 = n >> 2;
    const int krow = ((b4 ^ (((b4 ^ (b4 >> 1)) & 1) * 3)) << 2) + (n & 3);
    const short* kp = kg + (size_t)(s0 * 32 + krow) * 16 + 8 * g2;   // +512/step
    const short* vp;
    int vinc;
    if (n < 16) { vp = vtg + (size_t)n * vstride + s0 * 32 + 8 * g2; vinc = 32; }
    else        { vp = onesb + 8 * g2; vinc = 0; }

    // 3-deep prologue (up to 3-step pointer overrun stays inside workspace)
    s8v kf0 = *(const s8v*)kp; kp += 512;
    s8v va0 = *(const s8v*)vp; s8v vb0 = *(const s8v*)(vp + 16); vp += vinc;
    s8v kf1 = *(const s8v*)kp; kp += 512;
    s8v va1 = *(const s8v*)vp; s8v vb1 = *(const s8v*)(vp + 16); vp += vinc;
    s8v kf2 = *(const s8v*)kp; kp += 512;
    s8v va2 = *(const s8v*)vp; s8v vb2 = *(const s8v*)(vp + 16); vp += vinc;

    oA = zf16(); oB = zf16();
    for (int s = s0; s < s1; s++) {
        f16v sA = __builtin_amdgcn_mfma_f32_32x32x16_bf16(kf0, qfA, zf16(), 0, 0, 0);
        f16v sB = __builtin_amdgcn_mfma_f32_32x32x16_bf16(kf0, qfB, zf16(), 0, 0, 0);

        float pA[16], pB[16];
#pragma unroll
        for (int r = 0; r < 16; r++) { pA[r] = EXP2(sA[r]); pB[r] = EXP2(sB[r]); }
        u4v a1, a2, b1, b2;
        a1[0]=tpack(pA[1],pA[0]);   a1[1]=tpack(pA[3],pA[2]);
        a1[2]=tpack(pA[5],pA[4]);   a1[3]=tpack(pA[7],pA[6]);
        a2[0]=tpack(pA[9],pA[8]);   a2[1]=tpack(pA[11],pA[10]);
        a2[2]=tpack(pA[13],pA[12]); a2[3]=tpack(pA[15],pA[14]);
        b1[0]=tpack(pB[1],pB[0]);   b1[1]=tpack(pB[3],pB[2]);
        b1[2]=tpack(pB[5],pB[4]);   b1[3]=tpack(pB[7],pB[6]);
        b2[0]=tpack(pB[9],pB[8]);   b2[1]=tpack(pB[11],pB[10]);
        b2[2]=tpack(pB[13],pB[12]); b2[3]=tpack(pB[15],pB[14]);
        s8v pfA1 = __builtin_bit_cast(s8v, a1);
        s8v pfA2 = __builtin_bit_cast(s8v, a2);
        s8v pfB1 = __builtin_bit_cast(s8v, b1);
        s8v pfB2 = __builtin_bit_cast(s8v, b2);

        oA = __builtin_amdgcn_mfma_f32_32x32x16_bf16(pfA1, va0, oA, 0, 0, 0);
        oB = __builtin_amdgcn_mfma_f32_32x32x16_bf16(pfB1, va0, oB, 0, 0, 0);
        oA = __builtin_amdgcn_mfma_f32_32x32x16_bf16(pfA2, vb0, oA, 0, 0, 0);
        oB = __builtin_amdgcn_mfma_f32_32x32x16_bf16(pfB2, vb0, oB, 0, 0, 0);

        // rotate pipeline and issue step s+3
        kf0 = kf1; va0 = va1; vb0 = vb1;
        kf1 = kf2; va1 = va2; vb1 = vb2;
        kf2 = *(const s8v*)kp; kp += 512;
        va2 = *(const s8v*)vp; vb2 = *(const s8v*)(vp + 16); vp += vinc;
    }
}

__device__ __forceinline__ void attn_epilogue(
    const f16v oacc, short* __restrict__ obase, const int orowstride,
    const int qt0, const int nq, const int lane)
{
    const int n = lane & 31, g2 = lane >> 5;
#pragma unroll
    for (int r = 0; r < 16; r++) {
        float l = __shfl_xor(oacc[r], 16);
        float o = oacc[r] * RCP(l);
        const int q = qt0 + (r & 3) + 8 * (r >> 2) + 4 * g2;
        if (n < 16 && q < nq)
            obase[(size_t)q * orowstride + n] = f2bf(o);
    }
}

// ---------------------------------------------------------------------------
// Kernel 2: ALL attention. st: dual-qtile job per block, 4 waves split the
// 50 K-steps, TREE combine. XCD-affinity remap: the 25 qpair-blocks of one
// bh share blockIdx%8 -> same XCD -> K/V slice (100KB) resident in its L2.
// blocks [0,1600): st | [1600,2400): t | [2400,3424): s
// ---------------------------------------------------------------------------
__global__ __launch_bounds__(256, 4) void attn_all(
    const short* __restrict__ q0, const short* __restrict__ k0, const short* __restrict__ vt0,
    const short* __restrict__ q1, const short* __restrict__ k1, const short* __restrict__ vt1,
    const short* __restrict__ q2, const short* __restrict__ k2, const short* __restrict__ vt2,
    const short* __restrict__ onesb,
    short* __restrict__ ob0, short* __restrict__ ob1, short* __restrict__ ob2)
{
    __shared__ float red[2][2][64][17];  // 17.4 KB (st only), conflict-free stride
    const int blk = blockIdx.x;
    const int wave = threadIdx.x >> 6, lane = threadIdx.x & 63;

    if (blk < 1600) {                    // ---- st: N=1600; 2 qtiles, 4-way K split
        const int xcd = blk & 7, slot = blk >> 3;       // XCD-affinity remap
        const int bh  = xcd * 8 + slot / 25;            // all 25 qpairs of bh on 1 XCD
        const int qt0 = (slot % 25) * 64;
        const int batch = bh >> 3, h = bh & 7;
        const short* qg = q2 + (size_t)bh * 25600;
        const s8v qfA = load_qfrag(qg, qt0, lane);
        const s8v qfB = load_qfrag(qg, qt0 + 32, lane);
        const int s0 = (50 * wave) >> 2, s1 = (50 * (wave + 1)) >> 2;  // 12-13 steps
        f16v oA, oB;
        attn_loop2(k2 + (size_t)bh * 25600,
                   vt2 + (size_t)batch * 204800 + (size_t)h * 25600, 1600,
                   onesb, qfA, qfB, lane, s0, s1, oA, oB);

        // round 1: waves 2,3 publish; waves 0,1 accumulate partner (wave+2)
        if (wave >= 2) {
#pragma unroll
            for (int j = 0; j < 16; j++) {
                red[wave - 2][0][lane][j] = oA[j];
                red[wave - 2][1][lane][j] = oB[j];
            }
        }
        __syncthreads();
        if (wave < 2) {
#pragma unroll
            for (int j = 0; j < 16; j++) {
                oA[j] += red[wave][0][lane][j];
                oB[j] += red[wave][1][lane][j];
            }
        }
        __syncthreads();
        // round 2: wave0 publishes its B half, wave1 its A half (slot 0 reuse)
        if (wave == 0) {
#pragma unroll
            for (int j = 0; j < 16; j++) red[0][0][lane][j] = oB[j];
        } else if (wave == 1) {
#pragma unroll
            for (int j = 0; j < 16; j++) red[0][1][lane][j] = oA[j];
        }
        __syncthreads();
        short* obase = ob2 + (size_t)batch * 204800 + h * 16;
        if (wave == 0) {
#pragma unroll
            for (int j = 0; j < 16; j++) oA[j] += red[0][1][lane][j];
            attn_epilogue(oA, obase, 128, qt0, 1600, lane);
        } else if (wave == 1) {
#pragma unroll
            for (int j = 0; j < 16; j++) oB[j] += red[0][0][lane][j];
            attn_epilogue(oB, obase, 128, qt0 + 32, 1600, lane);
        }
    } else if (blk < 2400) {             // ---- t: N=64, 2 steps, 1 wave/job
        const int wid = (blk - 1600) * 4 + wave;
        const int bh = wid >> 1, qt0 = (wid & 1) * 32;
        const int bn = bh >> 3, h = bh & 7;
        const s8v qf = load_qfrag(q0 + (size_t)bh * 1024, qt0, lane);
        f16v oacc = attn_loop<false>(k0 + (size_t)bh * 1024,
                                     vt0 + (size_t)bh * 1024, 64,
                                     onesb, qf, lane, 0, 2);
        attn_epilogue(oacc, ob0 + (size_t)bn * 8192 + h * 16, 128, qt0, 64, lane);
    } else {                             // ---- s: N=25, 1 step, masked
        const int bh = (blk - 2400) * 4 + wave;   // bt*8 + h, < 4096
        const int bt = bh >> 3, h = bh & 7;
        const int b_ = bt >> 6, t_ = bt & 63;
        const s8v qf = load_qfrag(q1 + (size_t)bh * 400, 0, lane);
        f16v oacc = attn_loop<true>(k1 + (size_t)bh * 400,
                                    vt1 + (size_t)bh * 512, 32,
                                    onesb, qf, lane, 0, 1);
        attn_epilogue(oacc, ob1 + (size_t)b_ * 204800 + t_ * 128 + h * 16,
                      8192, 0, 25, lane);
    }
}

// ---------------------------------------------------------------------------
// Kernel 3: output projection (bf16 ob in, MFMA, fused shuffle store) + id copy.
// blocks [0,2400): proj (br = blk/800) | [2400,2600): id group
// ---------------------------------------------------------------------------
__global__ __launch_bounds__(256) void projid(
    const short* __restrict__ ob0, const short* __restrict__ ob1,
    const short* __restrict__ ob2, const short* __restrict__ wsw,
    const float* __restrict__ bp0, const float* __restrict__ bp1,
    const float* __restrict__ bp2,
    const float* __restrict__ x, float* __restrict__ out)
{
    __shared__ unsigned short xl[64 * 130];
    const int blk = blockIdx.x, tid = threadIdx.x;

    if (blk < 2400) {
        const int br = blk / 800, t8 = blk % 800;
        const short* obb = (br == 0) ? ob0 : (br == 1) ? ob1 : ob2;
        const float* bp  = (br == 0) ? bp0 : (br == 1) ? bp1 : bp2;
        const short* wswb = wsw + 147456 + br * 16384;
        const int grp = br + 1;
        const int tok0 = t8 * 16;
        const int wave = tid >> 6, lane = tid & 63;
        const int c = lane & 15, gq = lane >> 4;

        // hoist ALL weight frags + biases (static indices)
        s8v wf[2][4];
        float bvv[2];
#pragma unroll
        for (int nti = 0; nti < 2; nti++) {
            const int nt = wave * 2 + nti;
            const short* bpw = wswb + ((size_t)(nt * 4) * 64 + lane) * 8;
#pragma unroll
            for (int ks = 0; ks < 4; ks++)
                wf[nti][ks] = *(const s8v*)(bpw + ks * 512);
            bvv[nti] = bp[nt * 16 + c];
        }

        s8v af[4];
#pragma unroll
        for (int ks = 0; ks < 4; ks++)
            af[ks] = *(const s8v*)(obb + (size_t)(tok0 + c) * 128 + ks * 32 + 8 * gq);

        const int bnn = t8 >> 2, b_ = bnn / 25, n_ = bnn % 25;
        const int t0 = (t8 & 3) * 16 + 4 * gq;

#pragma unroll
        for (int nti = 0; nti < 2; nti++) {
            const int nt = wave * 2 + nti;
            f4 acc = {0.f, 0.f, 0.f, 0.f};
#pragma unroll
            for (int ks = 0; ks < 4; ks++)
                acc = __builtin_amdgcn_mfma_f32_16x16x32_bf16(af[ks], wf[nti][ks], acc, 0, 0, 0);
            const int c2 = nt * 16 + c;
            const float bv = bvv[nti];
            float4 st = {acc[0]+bv, acc[1]+bv, acc[2]+bv, acc[3]+bv};
            *(float4*)(out + (size_t)b_ * 819200 + (size_t)(c2 * 4 + grp) * 1600
                           + n_ * 64 + t0) = st;
        }
    } else {
        const int bn = blk - 2400;
        const int b_ = bn / 25, n_ = bn % 25;
        for (int idx = tid; idx < 8192; idx += 256) {
            int row = idx >> 7, c2 = idx & 127;
            xl[row * 130 + c2] =
                (unsigned short)(__float_as_uint(x[(size_t)(bn * 64 + row) * 512 + c2]) >> 16);
        }
        __syncthreads();
        const int t_ = tid & 63, cg = tid >> 6;
        const size_t base = (size_t)b_ * 819200 + (size_t)n_ * 64 + t_;
#pragma unroll
        for (int i = 0; i < 32; i++) {
            int c2 = cg + 4 * i;
            out[base + (size_t)(c2 * 4 + 0) * 1600] =
                __uint_as_float((unsigned)xl[t_ * 130 + c2] << 16);
        }
    }
}

// ---------------------------------------------------------------------------
extern "C" void kernel_launch(void* const* d_in, const int* in_sizes, int n_in,
                              void* d_out, int out_size, void* d_ws, size_t ws_size,
                              hipStream_t stream)
{
    const float* x        = (const float*)d_in[0];
    const float* t_wqkv   = (const float*)d_in[1];
    const float* t_bqkv   = (const float*)d_in[2];
    const float* t_wproj  = (const float*)d_in[3];
    const float* t_bproj  = (const float*)d_in[4];
    const float* s_wqkv   = (const float*)d_in[5];
    const float* s_bqkv   = (const float*)d_in[6];
    const float* s_wproj  = (const float*)d_in[7];
    const float* s_bproj  = (const float*)d_in[8];
    const float* st_wqkv  = (const float*)d_in[9];
    const float* st_bqkv  = (const float*)d_in[10];
    const float* st_wproj = (const float*)d_in[11];
    const float* st_bproj = (const float*)d_in[12];

    short* wsw   = (short*)d_ws;            // 196608
    short* onesb = wsw + 196608ull;         // 2048 of bf16 1.0
    short* q0  = onesb + 2048ull;
    short* k0  = q0 + BUF;
    short* vt0 = k0 + BUF;
    short* q1  = vt0 + BUF;
    short* k1  = q1 + BUF;
    short* vt1 = k1 + BUF;                  // padded: 4096*16*32 = 2097152
    short* q2  = vt1 + 2097152ull;
    short* k2  = q2 + BUF;
    short* vt2 = k2 + BUF;
    short* ob0 = vt2 + BUF;
    short* ob1 = ob0 + BUF;
    short* ob2 = ob1 + BUF;
    float* out = (float*)d_out;

    prep<<<97, 256, 0, stream>>>(t_wqkv, s_wqkv, st_wqkv,
                                 t_wproj, s_wproj, st_wproj, wsw, onesb);
    qkv_all<<<2400, 256, 0, stream>>>(x, wsw, t_bqkv, s_bqkv, st_bqkv,
                                      q0, k0, vt0, q1, k1, vt1, q2, k2, vt2);
    attn_all<<<3424, 256, 0, stream>>>(q0, k0, vt0, q1, k1, vt1, q2, k2, vt2,
                                       onesb, ob0, ob1, ob2);
    projid<<<2600, 256, 0, stream>>>(ob0, ob1, ob2, wsw,
                                     t_bproj, s_bproj, st_bproj, x, out);
}